// Round 9
// baseline (413.835 us; speedup 1.0000x reference)
//
#include <hip/hip_runtime.h>

// GIN-2layer + pool + classifier for MI355X.
// R8 change (measured: k_mlp1 62us, VGPR=52 < live arrays(96+) -> scratch
// spills; 391 blocks -> 14% occupancy; VALUBusy 8.4% = latency-bound):
//   k_mlp1/k_mlp2 restructured thread-per-node -> lane-per-channel
//   (2 nodes/wave). Per-lane state is 4 scalars (no arrays, no spills);
//   matmul via __shfl(a,k,32) broadcast (unrolled, uniform k, convergent
//   32-groups); grid 391 -> 12500 blocks; IO coalesced 256B/wave.
// Kept: R7 unrolled k_agg, R6 counting-sort CSR, R5 BN reduce, R4 shfl fix.

#define H 32
#define FIN 128
#define AGG_BLOCKS 2048
#define BNRED_NB 64

#define BKT_SHIFT 9
#define BKT_SZ 512          // nodes per bucket; nbuck = ceil(N/512) = 196 <= 256
#define ACHUNK 4096         // edges per block in bhist/bucketA

__device__ __forceinline__ int lower_bound_i(const int* __restrict__ a, int n, int key) {
  int lo = 0, hi = n;
  while (lo < hi) { int mid = (lo + hi) >> 1; if (a[mid] < key) lo = mid + 1; else hi = mid; }
  return lo;
}

// ---- CSR build: two-level counting sort ----

__global__ __launch_bounds__(256) void k_bhist(const int* __restrict__ dst, int E,
                                               int* __restrict__ gbcnt) {
  __shared__ int cnt[256];
  int t = threadIdx.x;
  int e0 = blockIdx.x * ACHUNK, e1 = min(e0 + ACHUNK, E);
  cnt[t] = 0;
  __syncthreads();
  for (int i = e0 + t; i < e1; i += 256) atomicAdd(&cnt[dst[i] >> BKT_SHIFT], 1);
  __syncthreads();
  if (cnt[t] > 0) atomicAdd(&gbcnt[t], cnt[t]);
}

__global__ __launch_bounds__(256) void k_bscan(const int* __restrict__ gbcnt, int nbuck,
                                               int* __restrict__ bbase, int* __restrict__ bcur) {
  int t = threadIdx.x;
  __shared__ int sh[256];
  int v0 = (t < nbuck) ? gbcnt[t] : 0;
  sh[t] = v0;
  __syncthreads();
  for (int d = 1; d < 256; d <<= 1) {
    int v = (t >= d) ? sh[t - d] : 0;
    __syncthreads();
    sh[t] += v;
    __syncthreads();
  }
  int excl = sh[t] - v0;
  if (t < nbuck) { bbase[t] = excl; bcur[t] = excl; }
  if (t == 255) bbase[nbuck] = sh[255];
}

__global__ __launch_bounds__(256) void k_bucketA(const int* __restrict__ src, const int* __restrict__ dst,
                                                 int E, int* __restrict__ bcur,
                                                 unsigned* __restrict__ staging) {
  __shared__ int cnt[256];
  __shared__ int base[256];
  int t = threadIdx.x;
  int e0 = blockIdx.x * ACHUNK, e1 = min(e0 + ACHUNK, E);
  cnt[t] = 0;
  __syncthreads();
  for (int i = e0 + t; i < e1; i += 256) atomicAdd(&cnt[dst[i] >> BKT_SHIFT], 1);
  __syncthreads();
  int c = cnt[t];
  base[t] = (c > 0) ? atomicAdd(&bcur[t], c) : 0;
  __syncthreads();
  for (int i = e0 + t; i < e1; i += 256) {
    int d = dst[i];
    int p = atomicAdd(&base[d >> BKT_SHIFT], 1);
    staging[p] = ((unsigned)(d & (BKT_SZ - 1)) << 17) | (unsigned)src[i];
  }
}

// One block per bucket: per-node hist (512) + scan -> row_ptr slice + sorted csr.
__global__ __launch_bounds__(256) void k_bucketB(const unsigned* __restrict__ staging,
                                                 const int* __restrict__ bbase, int N,
                                                 int* __restrict__ row_ptr, int* __restrict__ csr) {
  __shared__ int cnt[BKT_SZ];
  __shared__ int ptr[BKT_SZ];
  __shared__ int sc[256];
  int t = threadIdx.x, b = blockIdx.x;
  int nb0 = b << BKT_SHIFT;
  int nb1 = min(nb0 + BKT_SZ, N);
  int seg0 = bbase[b];
  int len = bbase[b + 1] - seg0;
  cnt[t] = 0; cnt[t + 256] = 0;
  __syncthreads();
  for (int i = t; i < len; i += 256) atomicAdd(&cnt[staging[seg0 + i] >> 17], 1);
  __syncthreads();
  int s2 = cnt[2 * t] + cnt[2 * t + 1];
  sc[t] = s2;
  __syncthreads();
  for (int d = 1; d < 256; d <<= 1) {
    int v = (t >= d) ? sc[t - d] : 0;
    __syncthreads();
    sc[t] += v;
    __syncthreads();
  }
  int base0 = sc[t] - s2;
  ptr[2 * t] = base0;
  ptr[2 * t + 1] = base0 + cnt[2 * t];
  __syncthreads();
  int nn = nb1 - nb0;
  if (2 * t < nn)     row_ptr[nb0 + 2 * t]     = seg0 + ptr[2 * t];
  if (2 * t + 1 < nn) row_ptr[nb0 + 2 * t + 1] = seg0 + ptr[2 * t + 1];
  if (t == 0 && nb1 == N) row_ptr[N] = seg0 + len;
  __syncthreads();
  for (int i = t; i < len; i += 256) {
    unsigned e = staging[seg0 + i];
    int d = (int)(e >> 17);
    int k = atomicAdd(&ptr[d], 1);
    csr[seg0 + k] = (int)(e & 0x1FFFFu);
  }
}

// ---- main pipeline kernels ----

// y[N,32] = x[N,128] @ W[128,32].  128 nodes/block, thread tile 4 nodes x 4 cols.
__global__ __launch_bounds__(256) void k_gemm1(const float* __restrict__ x, const float* __restrict__ W,
                                               float* __restrict__ y, int N) {
  __shared__ __align__(16) float ws[FIN * H];   // 16 KB, [k][c]
  __shared__ __align__(16) float xs[128 * 33];  // k-chunk of 32 (+1 pad)
  int t = threadIdx.x;
  for (int i = t; i < FIN * H; i += 256) ws[i] = W[i];
  int nb = blockIdx.x * 128;
  int r0 = (t >> 3) * 4;   // 0..124
  int c0 = (t & 7) * 4;    // 0..28
  float acc[4][4] = {{0.f,0.f,0.f,0.f},{0.f,0.f,0.f,0.f},{0.f,0.f,0.f,0.f},{0.f,0.f,0.f,0.f}};
  for (int kb = 0; kb < FIN; kb += 32) {
    __syncthreads();
    for (int i = t; i < 1024; i += 256) {  // 1024 float4 = [128][32] chunk
      int n = i >> 3, k4 = (i & 7) * 4;
      float4 v = make_float4(0.f, 0.f, 0.f, 0.f);
      int gn = nb + n;
      if (gn < N) v = *(const float4*)&x[(size_t)gn * FIN + kb + k4];
      xs[n * 33 + k4 + 0] = v.x; xs[n * 33 + k4 + 1] = v.y;
      xs[n * 33 + k4 + 2] = v.z; xs[n * 33 + k4 + 3] = v.w;
    }
    __syncthreads();
#pragma unroll
    for (int k = 0; k < 32; ++k) {
      float4 wv = *(const float4*)&ws[(kb + k) * H + c0];
      float x0 = xs[(r0 + 0) * 33 + k];
      float x1 = xs[(r0 + 1) * 33 + k];
      float x2 = xs[(r0 + 2) * 33 + k];
      float x3 = xs[(r0 + 3) * 33 + k];
      acc[0][0] += x0 * wv.x; acc[0][1] += x0 * wv.y; acc[0][2] += x0 * wv.z; acc[0][3] += x0 * wv.w;
      acc[1][0] += x1 * wv.x; acc[1][1] += x1 * wv.y; acc[1][2] += x1 * wv.z; acc[1][3] += x1 * wv.w;
      acc[2][0] += x2 * wv.x; acc[2][1] += x2 * wv.y; acc[2][2] += x2 * wv.z; acc[2][3] += x2 * wv.w;
      acc[3][0] += x3 * wv.x; acc[3][1] += x3 * wv.y; acc[3][2] += x3 * wv.z; acc[3][3] += x3 * wv.w;
    }
  }
#pragma unroll
  for (int r = 0; r < 4; ++r) {
    int gn = nb + r0 + r;
    if (gn < N)
      *(float4*)&y[(size_t)gn * H + c0] = make_float4(acc[r][0], acc[r][1], acc[r][2], acc[r][3]);
  }
}

// hout[n] = y[n] + bias + sum_{j in in(n)} y[j];  also per-block BN partials.
// One wave per node, lane = 2-edge x 32-channel. Gather loop 4-deep unrolled.
__global__ __launch_bounds__(256) void k_agg(const float* __restrict__ y, const float* __restrict__ bias,
                                             const int* __restrict__ row_ptr, const int* __restrict__ csr,
                                             float* __restrict__ hout, float* __restrict__ bn_part, int N) {
  int wid = threadIdx.x >> 6, lane = threadIdx.x & 63;
  int c = lane & 31, ep = lane >> 5;
  float rsum = 0.f, rsq = 0.f;
  float bc = bias[c];
  int stride = gridDim.x * 4;
  for (int n = blockIdx.x * 4 + wid; n < N; n += stride) {
    int beg = row_ptr[n], end = row_ptr[n + 1];
    float acc = 0.f;
    for (int b0 = beg; b0 < end; b0 += 64) {
      int m = end - b0; if (m > 64) m = 64;          // wave-uniform
      int idx = (lane < m) ? csr[b0 + lane] : 0;
      int r = 0;
      for (; r + 8 <= m; r += 8) {                   // unrolled: s = r+2q+ep <= m-2+1 < m
        int j0 = __shfl(idx, r + 0 + ep, 64);
        int j1 = __shfl(idx, r + 2 + ep, 64);
        int j2 = __shfl(idx, r + 4 + ep, 64);
        int j3 = __shfl(idx, r + 6 + ep, 64);
        float v0 = y[(size_t)j0 * H + c];
        float v1 = y[(size_t)j1 * H + c];
        float v2 = y[(size_t)j2 * H + c];
        float v3 = y[(size_t)j3 * H + c];
        acc += (v0 + v1) + (v2 + v3);
      }
      for (; r < m; r += 2) {                        // wave-uniform tail
        int s = r + ep;                              // may be == m when m odd, ep==1
        int j = __shfl(idx, (s < m) ? s : 0, 64);    // full-exec shfl, valid src
        float val = y[(size_t)j * H + c];
        if (s < m) acc += val;                       // predicated accumulate
      }
    }
    acc += __shfl_xor(acc, 32, 64);
    float v = acc + y[(size_t)n * H + c] + bc;
    if (ep == 0) {
      hout[(size_t)n * H + c] = v;
      rsum += v; rsq += v * v;
    }
  }
  __shared__ float bsum[4][H], bsq[4][H];
  if (ep == 0) { bsum[wid][c] = rsum; bsq[wid][c] = rsq; }
  __syncthreads();
  if (threadIdx.x < H) {
    int cc = threadIdx.x;
    bn_part[(size_t)blockIdx.x * 64 + cc]     = bsum[0][cc] + bsum[1][cc] + bsum[2][cc] + bsum[3][cc];
    bn_part[(size_t)blockIdx.x * 64 + H + cc] = bsq[0][cc] + bsq[1][cc] + bsq[2][cc] + bsq[3][cc];
  }
}

// Stage A: 64 blocks, block b reduces rows [32b, 32b+32) of part[2048][64] -> part2[b][64].
__global__ __launch_bounds__(256) void k_bnred(const float* __restrict__ part,
                                               float* __restrict__ part2) {
  int t = threadIdx.x, b = blockIdx.x;
  int col = t & 63, q = t >> 6;                       // 4 row-groups x 8 rows
  int rpb = AGG_BLOCKS / BNRED_NB;                    // 32
  int r0 = b * rpb + q * (rpb / 4);
  float s = 0.f;
  for (int r = r0; r < r0 + rpb / 4; ++r) s += part[(size_t)r * 64 + col];
  __shared__ float red[4][64];
  red[q][col] = s;
  __syncthreads();
  if (t < 64) part2[(size_t)b * 64 + t] = red[0][t] + red[1][t] + red[2][t] + red[3][t];
}

// Stage B: 1 block reduces part[nblk][64] (nblk=64 now) -> scale/shift.
__global__ __launch_bounds__(256) void k_bnfin(const float* __restrict__ part, int nblk,
                                               const float* __restrict__ gma, const float* __restrict__ bet,
                                               float* __restrict__ sc, float invN) {
  int t = threadIdx.x;
  int col = t & 63, q = t >> 6;   // 4 slices
  int per = nblk >> 2;
  float s = 0.f;
  for (int r = q * per; r < (q + 1) * per; ++r) s += part[(size_t)r * 64 + col];
  __shared__ float red[4][64];
  __shared__ float tot[64];
  red[q][col] = s;
  __syncthreads();
  if (t < 64) tot[t] = red[0][t] + red[1][t] + red[2][t] + red[3][t];
  __syncthreads();
  if (t < H) {
    float mean = tot[t] * invN;
    float var = tot[H + t] * invN - mean * mean;
    float scale = gma[t] * rsqrtf(var + 1e-5f);
    sc[t] = scale;
    sc[H + t] = bet[t] - mean * scale;
  }
}

// y2 = relu(relu(BN1(h1)) @ W2 + b2) @ W3.
// Lane-per-channel, 2 nodes/wave: per-lane state is 4 scalars (no spills).
// Matmul via __shfl(a,k,32): k is an unrolled constant; each 32-lane group is
// self-contained and fully convergent (N even -> both nodes of a wave exit
// together), so every shfl source lane is active.
__global__ __launch_bounds__(256) void k_mlp1(const float* __restrict__ h1, const float* __restrict__ sc,
                                              const float* __restrict__ W2, const float* __restrict__ b2,
                                              const float* __restrict__ W3, float* __restrict__ y2, int N) {
  __shared__ __align__(16) float ws2[H * H], ws3[H * H];
  int t = threadIdx.x;
  for (int i = t; i < H * H; i += 256) { ws2[i] = W2[i]; ws3[i] = W3[i]; }
  __syncthreads();
  int lane = t & 63, wid = t >> 6;
  int c = lane & 31;
  int n = (blockIdx.x * 4 + wid) * 2 + (lane >> 5);
  if (n >= N) return;
  float h = h1[(size_t)n * H + c];
  float a = fmaxf(h * sc[c] + sc[H + c], 0.f);
  float u = b2[c];
#pragma unroll
  for (int k = 0; k < H; ++k)
    u += __shfl(a, k, 32) * ws2[k * H + c];
  u = fmaxf(u, 0.f);
  float o = 0.f;
#pragma unroll
  for (int k = 0; k < H; ++k)
    o += __shfl(u, k, 32) * ws3[k * H + c];
  y2[(size_t)n * H + c] = o;   // b3 is added during aggregation (linearity)
}

// h2 = relu(BN2(h2pre)) @ W4 + b4   (no trailing relu). Same wave structure.
__global__ __launch_bounds__(256) void k_mlp2(const float* __restrict__ hpre, const float* __restrict__ sc,
                                              const float* __restrict__ W4, const float* __restrict__ b4,
                                              float* __restrict__ h2, int N) {
  __shared__ __align__(16) float ws4[H * H];
  int t = threadIdx.x;
  for (int i = t; i < H * H; i += 256) ws4[i] = W4[i];
  __syncthreads();
  int lane = t & 63, wid = t >> 6;
  int c = lane & 31;
  int n = (blockIdx.x * 4 + wid) * 2 + (lane >> 5);
  if (n >= N) return;
  float h = hpre[(size_t)n * H + c];
  float a = fmaxf(h * sc[c] + sc[H + c], 0.f);
  float o = b4[c];
#pragma unroll
  for (int k = 0; k < H; ++k)
    o += __shfl(a, k, 32) * ws4[k * H + c];
  h2[(size_t)n * H + c] = o;
}

// batch is sorted: graph g owns node range [lb(g), lb(g+1)). Wave per graph, mean||max -> z[G,64].
__global__ __launch_bounds__(256) void k_pool(const float* __restrict__ h2, const int* __restrict__ batch,
                                              int N, int G, float* __restrict__ z) {
  int wid = threadIdx.x >> 6, lane = threadIdx.x & 63;
  int g = blockIdx.x * 4 + wid;
  if (g >= G) return;
  int beg = lower_bound_i(batch, N, g);
  int end = lower_bound_i(batch, N, g + 1);
  int c = lane & 31, ep = lane >> 5;
  float s = 0.f, m = -3.402823466e38f;
  for (int i = beg + ep; i < end; i += 2) {
    float v = h2[(size_t)i * H + c];
    s += v; m = fmaxf(m, v);
  }
  s += __shfl_xor(s, 32, 64);
  m = fmaxf(m, __shfl_xor(m, 32, 64));
  if (ep == 0) {
    int cnt = end - beg;
    z[(size_t)g * 64 + c]     = (cnt > 0) ? s / (float)cnt : 0.f;
    z[(size_t)g * 64 + H + c] = (cnt > 0) ? m : 0.f;
  }
}

// out = relu(z @ Wc1 + bc1) @ Wc2 + bc2 ; thread per graph.
__global__ __launch_bounds__(256) void k_cls(const float* __restrict__ z, const float* __restrict__ Wc1,
                                             const float* __restrict__ bc1, const float* __restrict__ Wc2,
                                             const float* __restrict__ bc2, float* __restrict__ out, int G) {
  __shared__ __align__(16) float w1s[64 * H];
  __shared__ float w2s[H * 2], b1s[H], b2s[2];
  int t = threadIdx.x;
  for (int i = t; i < 64 * H; i += 256) w1s[i] = Wc1[i];
  if (t < H * 2) w2s[t] = Wc2[t];
  if (t < H) b1s[t] = bc1[t];
  if (t < 2) b2s[t] = bc2[t];
  __syncthreads();
  int g = blockIdx.x * 256 + t;
  if (g >= G) return;
  float zr[64], u[H];
  const float4* zp = (const float4*)&z[(size_t)g * 64];
#pragma unroll
  for (int q = 0; q < 16; ++q) {
    float4 v = zp[q];
    zr[q * 4 + 0] = v.x; zr[q * 4 + 1] = v.y; zr[q * 4 + 2] = v.z; zr[q * 4 + 3] = v.w;
  }
#pragma unroll
  for (int c = 0; c < H; ++c) u[c] = b1s[c];
#pragma unroll
  for (int k = 0; k < 64; ++k) {
    float av = zr[k];
    const float4* wr = (const float4*)&w1s[k * H];
#pragma unroll
    for (int q = 0; q < H / 4; ++q) {
      float4 wv = wr[q];
      u[q * 4 + 0] += av * wv.x; u[q * 4 + 1] += av * wv.y;
      u[q * 4 + 2] += av * wv.z; u[q * 4 + 3] += av * wv.w;
    }
  }
  float o0 = b2s[0], o1 = b2s[1];
#pragma unroll
  for (int k = 0; k < H; ++k) {
    float uv = fmaxf(u[k], 0.f);
    o0 += uv * w2s[k * 2 + 0];
    o1 += uv * w2s[k * 2 + 1];
  }
  out[(size_t)g * 2 + 0] = o0;
  out[(size_t)g * 2 + 1] = o1;
}

extern "C" void kernel_launch(void* const* d_in, const int* in_sizes, int n_in,
                              void* d_out, int out_size, void* d_ws, size_t ws_size,
                              hipStream_t stream) {
  const float* x    = (const float*)d_in[0];
  const int*   eidx = (const int*)d_in[1];
  const int*   batch= (const int*)d_in[2];
  const float* W1 = (const float*)d_in[3];
  const float* b1 = (const float*)d_in[4];
  const float* g1 = (const float*)d_in[5];
  const float* be1= (const float*)d_in[6];
  const float* W2 = (const float*)d_in[7];
  const float* b2 = (const float*)d_in[8];
  const float* W3 = (const float*)d_in[9];
  const float* b3 = (const float*)d_in[10];
  const float* g2 = (const float*)d_in[11];
  const float* be2= (const float*)d_in[12];
  const float* W4 = (const float*)d_in[13];
  const float* b4 = (const float*)d_in[14];
  const float* Wc1= (const float*)d_in[15];
  const float* bc1= (const float*)d_in[16];
  const float* Wc2= (const float*)d_in[17];
  const float* bc2= (const float*)d_in[18];
  (void)n_in; (void)ws_size;

  int N = in_sizes[2];       // 100000
  int E = in_sizes[1] / 2;   // 1600000
  int G = out_size / 2;      // 1000
  int nbuck = (N + BKT_SZ - 1) >> BKT_SHIFT;   // 196
  const int* srcv = eidx;
  const int* dstv = eidx + E;

  char* w = (char*)d_ws;
  auto carve = [&](size_t bytes) { void* p = (void*)w; w += (bytes + 255) & ~(size_t)255; return p; };
  float*    bufA    = (float*)carve((size_t)N * H * 4);      // y1 -> y2 -> h2
  float*    bufB    = (float*)carve((size_t)N * H * 4);      // h1 -> h2pre
  int*      row_ptr = (int*)carve((size_t)(N + 1) * 4);
  int*      csr     = (int*)carve((size_t)E * 4);
  unsigned* staging = (unsigned*)carve((size_t)E * 4);
  int*      gbcnt   = (int*)carve(256 * 4);
  int*      bbase   = (int*)carve(257 * 4);
  int*      bcur    = (int*)carve(256 * 4);
  float*    bnp     = (float*)carve((size_t)AGG_BLOCKS * 64 * 4);
  float*    bnp2    = (float*)carve((size_t)BNRED_NB * 64 * 4);
  float*    sc1     = (float*)carve(64 * 4);
  float*    sc2     = (float*)carve(64 * 4);
  float*    z       = (float*)carve((size_t)G * 64 * 4);

  int abk = (E + ACHUNK - 1) / ACHUNK;   // 391
  int mlpblk = ((N + 1) / 2 + 3) / 4;    // 2 nodes/wave, 4 waves/block -> 12500

  hipMemsetAsync(gbcnt, 0, 256 * 4, stream);
  k_bhist<<<abk, 256, 0, stream>>>(dstv, E, gbcnt);
  k_bscan<<<1, 256, 0, stream>>>(gbcnt, nbuck, bbase, bcur);
  k_bucketA<<<abk, 256, 0, stream>>>(srcv, dstv, E, bcur, staging);
  k_bucketB<<<nbuck, 256, 0, stream>>>(staging, bbase, N, row_ptr, csr);
  k_gemm1<<<(N + 127) / 128, 256, 0, stream>>>(x, W1, bufA, N);
  k_agg<<<AGG_BLOCKS, 256, 0, stream>>>(bufA, b1, row_ptr, csr, bufB, bnp, N);
  k_bnred<<<BNRED_NB, 256, 0, stream>>>(bnp, bnp2);
  k_bnfin<<<1, 256, 0, stream>>>(bnp2, BNRED_NB, g1, be1, sc1, 1.0f / (float)N);
  k_mlp1<<<mlpblk, 256, 0, stream>>>(bufB, sc1, W2, b2, W3, bufA, N);
  k_agg<<<AGG_BLOCKS, 256, 0, stream>>>(bufA, b3, row_ptr, csr, bufB, bnp, N);
  k_bnred<<<BNRED_NB, 256, 0, stream>>>(bnp, bnp2);
  k_bnfin<<<1, 256, 0, stream>>>(bnp2, BNRED_NB, g2, be2, sc2, 1.0f / (float)N);
  k_mlp2<<<mlpblk, 256, 0, stream>>>(bufB, sc2, W4, b4, bufA, N);
  k_pool<<<(G + 3) / 4, 256, 0, stream>>>(bufA, batch, N, G, z);
  k_cls<<<(G + 255) / 256, 256, 0, stream>>>(z, Wc1, bc1, Wc2, bc2, (float*)d_out, G);
}

// Round 10
// 389.596 us; speedup vs baseline: 1.0622x; 1.0622x over previous
//
#include <hip/hip_runtime.h>

// GIN-2layer + pool + classifier for MI355X.
// R9 post-mortem: R8's shfl-MLP fixed occupancy/spills but is LDS-pipe-bound
// (128 LDS wave-instr per 64 FMA wave-instr; VALUBusy 17%, conflicts 0).
// R10 change: k_mlp1/k_mlp2 rebuilt in k_gemm1's register-tiled form:
//   128-node tile, BN+relu fused into LDS staging, 4x4 acc/thread,
//   padded [128][33] tiles (broadcast + 8-bank spread -> 0 conflicts).
//   ~3x fewer LDS instrs/node, 16 FMA per LDS read-quad.
// Kept: R7 unrolled k_agg, R6 counting-sort CSR, R5 BN reduce, R4 shfl fix.

#define H 32
#define FIN 128
#define AGG_BLOCKS 2048
#define BNRED_NB 64

#define BKT_SHIFT 9
#define BKT_SZ 512          // nodes per bucket; nbuck = ceil(N/512) = 196 <= 256
#define ACHUNK 4096         // edges per block in bhist/bucketA

__device__ __forceinline__ int lower_bound_i(const int* __restrict__ a, int n, int key) {
  int lo = 0, hi = n;
  while (lo < hi) { int mid = (lo + hi) >> 1; if (a[mid] < key) lo = mid + 1; else hi = mid; }
  return lo;
}

// ---- CSR build: two-level counting sort ----

__global__ __launch_bounds__(256) void k_bhist(const int* __restrict__ dst, int E,
                                               int* __restrict__ gbcnt) {
  __shared__ int cnt[256];
  int t = threadIdx.x;
  int e0 = blockIdx.x * ACHUNK, e1 = min(e0 + ACHUNK, E);
  cnt[t] = 0;
  __syncthreads();
  for (int i = e0 + t; i < e1; i += 256) atomicAdd(&cnt[dst[i] >> BKT_SHIFT], 1);
  __syncthreads();
  if (cnt[t] > 0) atomicAdd(&gbcnt[t], cnt[t]);
}

__global__ __launch_bounds__(256) void k_bscan(const int* __restrict__ gbcnt, int nbuck,
                                               int* __restrict__ bbase, int* __restrict__ bcur) {
  int t = threadIdx.x;
  __shared__ int sh[256];
  int v0 = (t < nbuck) ? gbcnt[t] : 0;
  sh[t] = v0;
  __syncthreads();
  for (int d = 1; d < 256; d <<= 1) {
    int v = (t >= d) ? sh[t - d] : 0;
    __syncthreads();
    sh[t] += v;
    __syncthreads();
  }
  int excl = sh[t] - v0;
  if (t < nbuck) { bbase[t] = excl; bcur[t] = excl; }
  if (t == 255) bbase[nbuck] = sh[255];
}

__global__ __launch_bounds__(256) void k_bucketA(const int* __restrict__ src, const int* __restrict__ dst,
                                                 int E, int* __restrict__ bcur,
                                                 unsigned* __restrict__ staging) {
  __shared__ int cnt[256];
  __shared__ int base[256];
  int t = threadIdx.x;
  int e0 = blockIdx.x * ACHUNK, e1 = min(e0 + ACHUNK, E);
  cnt[t] = 0;
  __syncthreads();
  for (int i = e0 + t; i < e1; i += 256) atomicAdd(&cnt[dst[i] >> BKT_SHIFT], 1);
  __syncthreads();
  int c = cnt[t];
  base[t] = (c > 0) ? atomicAdd(&bcur[t], c) : 0;
  __syncthreads();
  for (int i = e0 + t; i < e1; i += 256) {
    int d = dst[i];
    int p = atomicAdd(&base[d >> BKT_SHIFT], 1);
    staging[p] = ((unsigned)(d & (BKT_SZ - 1)) << 17) | (unsigned)src[i];
  }
}

// One block per bucket: per-node hist (512) + scan -> row_ptr slice + sorted csr.
__global__ __launch_bounds__(256) void k_bucketB(const unsigned* __restrict__ staging,
                                                 const int* __restrict__ bbase, int N,
                                                 int* __restrict__ row_ptr, int* __restrict__ csr) {
  __shared__ int cnt[BKT_SZ];
  __shared__ int ptr[BKT_SZ];
  __shared__ int sc[256];
  int t = threadIdx.x, b = blockIdx.x;
  int nb0 = b << BKT_SHIFT;
  int nb1 = min(nb0 + BKT_SZ, N);
  int seg0 = bbase[b];
  int len = bbase[b + 1] - seg0;
  cnt[t] = 0; cnt[t + 256] = 0;
  __syncthreads();
  for (int i = t; i < len; i += 256) atomicAdd(&cnt[staging[seg0 + i] >> 17], 1);
  __syncthreads();
  int s2 = cnt[2 * t] + cnt[2 * t + 1];
  sc[t] = s2;
  __syncthreads();
  for (int d = 1; d < 256; d <<= 1) {
    int v = (t >= d) ? sc[t - d] : 0;
    __syncthreads();
    sc[t] += v;
    __syncthreads();
  }
  int base0 = sc[t] - s2;
  ptr[2 * t] = base0;
  ptr[2 * t + 1] = base0 + cnt[2 * t];
  __syncthreads();
  int nn = nb1 - nb0;
  if (2 * t < nn)     row_ptr[nb0 + 2 * t]     = seg0 + ptr[2 * t];
  if (2 * t + 1 < nn) row_ptr[nb0 + 2 * t + 1] = seg0 + ptr[2 * t + 1];
  if (t == 0 && nb1 == N) row_ptr[N] = seg0 + len;
  __syncthreads();
  for (int i = t; i < len; i += 256) {
    unsigned e = staging[seg0 + i];
    int d = (int)(e >> 17);
    int k = atomicAdd(&ptr[d], 1);
    csr[seg0 + k] = (int)(e & 0x1FFFFu);
  }
}

// ---- main pipeline kernels ----

// y[N,32] = x[N,128] @ W[128,32].  128 nodes/block, thread tile 4 nodes x 4 cols.
__global__ __launch_bounds__(256) void k_gemm1(const float* __restrict__ x, const float* __restrict__ W,
                                               float* __restrict__ y, int N) {
  __shared__ __align__(16) float ws[FIN * H];   // 16 KB, [k][c]
  __shared__ __align__(16) float xs[128 * 33];  // k-chunk of 32 (+1 pad)
  int t = threadIdx.x;
  for (int i = t; i < FIN * H; i += 256) ws[i] = W[i];
  int nb = blockIdx.x * 128;
  int r0 = (t >> 3) * 4;   // 0..124
  int c0 = (t & 7) * 4;    // 0..28
  float acc[4][4] = {{0.f,0.f,0.f,0.f},{0.f,0.f,0.f,0.f},{0.f,0.f,0.f,0.f},{0.f,0.f,0.f,0.f}};
  for (int kb = 0; kb < FIN; kb += 32) {
    __syncthreads();
    for (int i = t; i < 1024; i += 256) {  // 1024 float4 = [128][32] chunk
      int n = i >> 3, k4 = (i & 7) * 4;
      float4 v = make_float4(0.f, 0.f, 0.f, 0.f);
      int gn = nb + n;
      if (gn < N) v = *(const float4*)&x[(size_t)gn * FIN + kb + k4];
      xs[n * 33 + k4 + 0] = v.x; xs[n * 33 + k4 + 1] = v.y;
      xs[n * 33 + k4 + 2] = v.z; xs[n * 33 + k4 + 3] = v.w;
    }
    __syncthreads();
#pragma unroll
    for (int k = 0; k < 32; ++k) {
      float4 wv = *(const float4*)&ws[(kb + k) * H + c0];
      float x0 = xs[(r0 + 0) * 33 + k];
      float x1 = xs[(r0 + 1) * 33 + k];
      float x2 = xs[(r0 + 2) * 33 + k];
      float x3 = xs[(r0 + 3) * 33 + k];
      acc[0][0] += x0 * wv.x; acc[0][1] += x0 * wv.y; acc[0][2] += x0 * wv.z; acc[0][3] += x0 * wv.w;
      acc[1][0] += x1 * wv.x; acc[1][1] += x1 * wv.y; acc[1][2] += x1 * wv.z; acc[1][3] += x1 * wv.w;
      acc[2][0] += x2 * wv.x; acc[2][1] += x2 * wv.y; acc[2][2] += x2 * wv.z; acc[2][3] += x2 * wv.w;
      acc[3][0] += x3 * wv.x; acc[3][1] += x3 * wv.y; acc[3][2] += x3 * wv.z; acc[3][3] += x3 * wv.w;
    }
  }
#pragma unroll
  for (int r = 0; r < 4; ++r) {
    int gn = nb + r0 + r;
    if (gn < N)
      *(float4*)&y[(size_t)gn * H + c0] = make_float4(acc[r][0], acc[r][1], acc[r][2], acc[r][3]);
  }
}

// hout[n] = y[n] + bias + sum_{j in in(n)} y[j];  also per-block BN partials.
// One wave per node, lane = 2-edge x 32-channel. Gather loop 4-deep unrolled.
__global__ __launch_bounds__(256) void k_agg(const float* __restrict__ y, const float* __restrict__ bias,
                                             const int* __restrict__ row_ptr, const int* __restrict__ csr,
                                             float* __restrict__ hout, float* __restrict__ bn_part, int N) {
  int wid = threadIdx.x >> 6, lane = threadIdx.x & 63;
  int c = lane & 31, ep = lane >> 5;
  float rsum = 0.f, rsq = 0.f;
  float bc = bias[c];
  int stride = gridDim.x * 4;
  for (int n = blockIdx.x * 4 + wid; n < N; n += stride) {
    int beg = row_ptr[n], end = row_ptr[n + 1];
    float acc = 0.f;
    for (int b0 = beg; b0 < end; b0 += 64) {
      int m = end - b0; if (m > 64) m = 64;          // wave-uniform
      int idx = (lane < m) ? csr[b0 + lane] : 0;
      int r = 0;
      for (; r + 8 <= m; r += 8) {                   // unrolled: s = r+2q+ep <= m-2+1 < m
        int j0 = __shfl(idx, r + 0 + ep, 64);
        int j1 = __shfl(idx, r + 2 + ep, 64);
        int j2 = __shfl(idx, r + 4 + ep, 64);
        int j3 = __shfl(idx, r + 6 + ep, 64);
        float v0 = y[(size_t)j0 * H + c];
        float v1 = y[(size_t)j1 * H + c];
        float v2 = y[(size_t)j2 * H + c];
        float v3 = y[(size_t)j3 * H + c];
        acc += (v0 + v1) + (v2 + v3);
      }
      for (; r < m; r += 2) {                        // wave-uniform tail
        int s = r + ep;                              // may be == m when m odd, ep==1
        int j = __shfl(idx, (s < m) ? s : 0, 64);    // full-exec shfl, valid src
        float val = y[(size_t)j * H + c];
        if (s < m) acc += val;                       // predicated accumulate
      }
    }
    acc += __shfl_xor(acc, 32, 64);
    float v = acc + y[(size_t)n * H + c] + bc;
    if (ep == 0) {
      hout[(size_t)n * H + c] = v;
      rsum += v; rsq += v * v;
    }
  }
  __shared__ float bsum[4][H], bsq[4][H];
  if (ep == 0) { bsum[wid][c] = rsum; bsq[wid][c] = rsq; }
  __syncthreads();
  if (threadIdx.x < H) {
    int cc = threadIdx.x;
    bn_part[(size_t)blockIdx.x * 64 + cc]     = bsum[0][cc] + bsum[1][cc] + bsum[2][cc] + bsum[3][cc];
    bn_part[(size_t)blockIdx.x * 64 + H + cc] = bsq[0][cc] + bsq[1][cc] + bsq[2][cc] + bsq[3][cc];
  }
}

// Stage A: 64 blocks, block b reduces rows [32b, 32b+32) of part[2048][64] -> part2[b][64].
__global__ __launch_bounds__(256) void k_bnred(const float* __restrict__ part,
                                               float* __restrict__ part2) {
  int t = threadIdx.x, b = blockIdx.x;
  int col = t & 63, q = t >> 6;                       // 4 row-groups x 8 rows
  int rpb = AGG_BLOCKS / BNRED_NB;                    // 32
  int r0 = b * rpb + q * (rpb / 4);
  float s = 0.f;
  for (int r = r0; r < r0 + rpb / 4; ++r) s += part[(size_t)r * 64 + col];
  __shared__ float red[4][64];
  red[q][col] = s;
  __syncthreads();
  if (t < 64) part2[(size_t)b * 64 + t] = red[0][t] + red[1][t] + red[2][t] + red[3][t];
}

// Stage B: 1 block reduces part[nblk][64] (nblk=64 now) -> scale/shift.
__global__ __launch_bounds__(256) void k_bnfin(const float* __restrict__ part, int nblk,
                                               const float* __restrict__ gma, const float* __restrict__ bet,
                                               float* __restrict__ sc, float invN) {
  int t = threadIdx.x;
  int col = t & 63, q = t >> 6;   // 4 slices
  int per = nblk >> 2;
  float s = 0.f;
  for (int r = q * per; r < (q + 1) * per; ++r) s += part[(size_t)r * 64 + col];
  __shared__ float red[4][64];
  __shared__ float tot[64];
  red[q][col] = s;
  __syncthreads();
  if (t < 64) tot[t] = red[0][t] + red[1][t] + red[2][t] + red[3][t];
  __syncthreads();
  if (t < H) {
    float mean = tot[t] * invN;
    float var = tot[H + t] * invN - mean * mean;
    float scale = gma[t] * rsqrtf(var + 1e-5f);
    sc[t] = scale;
    sc[H + t] = bet[t] - mean * scale;
  }
}

// y2 = relu(relu(BN1(h1)) @ W2 + b2) @ W3, gemm1-style register tiling.
// 128 nodes/block; BN+relu fused into LDS staging; thread tile 4 nodes x 4 cols;
// intermediate u tile bounced through LDS for the second matmul.
// Bank pattern: as[(r0+i)*33+k] -> 8 row-groups spread over 8 banks (33 mod 32 = 1),
// broadcast within each 8-lane group -> 0 conflicts (same as k_gemm1).
__global__ __launch_bounds__(256) void k_mlp1(const float* __restrict__ h1, const float* __restrict__ sc,
                                              const float* __restrict__ W2, const float* __restrict__ b2,
                                              const float* __restrict__ W3, float* __restrict__ y2, int N) {
  __shared__ __align__(16) float ws2[H * H], ws3[H * H];   // [k][c], 4KB each
  __shared__ __align__(16) float as[128 * 33];             // BN+relu'd input tile
  __shared__ __align__(16) float us[128 * 33];             // intermediate tile
  __shared__ float scs[2 * H], b2s[H];
  int t = threadIdx.x;
  for (int i = t; i < H * H; i += 256) { ws2[i] = W2[i]; ws3[i] = W3[i]; }
  if (t < 2 * H) scs[t] = sc[t];
  if (t < H) b2s[t] = b2[t];
  __syncthreads();
  int nb = blockIdx.x * 128;
  for (int i = t; i < 1024; i += 256) {        // stage: 1024 float4 = [128][32]
    int n = i >> 3, c4 = (i & 7) * 4;
    int gn = nb + n;
    float4 v = make_float4(0.f, 0.f, 0.f, 0.f);
    if (gn < N) v = *(const float4*)&h1[(size_t)gn * H + c4];
    as[n * 33 + c4 + 0] = fmaxf(v.x * scs[c4 + 0] + scs[H + c4 + 0], 0.f);
    as[n * 33 + c4 + 1] = fmaxf(v.y * scs[c4 + 1] + scs[H + c4 + 1], 0.f);
    as[n * 33 + c4 + 2] = fmaxf(v.z * scs[c4 + 2] + scs[H + c4 + 2], 0.f);
    as[n * 33 + c4 + 3] = fmaxf(v.w * scs[c4 + 3] + scs[H + c4 + 3], 0.f);
  }
  __syncthreads();
  int r0 = (t >> 3) * 4, c0 = (t & 7) * 4;
  float acc[4][4];
#pragma unroll
  for (int i = 0; i < 4; ++i)
#pragma unroll
    for (int j = 0; j < 4; ++j) acc[i][j] = b2s[c0 + j];
#pragma unroll
  for (int k = 0; k < H; ++k) {
    float4 wv = *(const float4*)&ws2[k * H + c0];
    float x0 = as[(r0 + 0) * 33 + k];
    float x1 = as[(r0 + 1) * 33 + k];
    float x2 = as[(r0 + 2) * 33 + k];
    float x3 = as[(r0 + 3) * 33 + k];
    acc[0][0] += x0 * wv.x; acc[0][1] += x0 * wv.y; acc[0][2] += x0 * wv.z; acc[0][3] += x0 * wv.w;
    acc[1][0] += x1 * wv.x; acc[1][1] += x1 * wv.y; acc[1][2] += x1 * wv.z; acc[1][3] += x1 * wv.w;
    acc[2][0] += x2 * wv.x; acc[2][1] += x2 * wv.y; acc[2][2] += x2 * wv.z; acc[2][3] += x2 * wv.w;
    acc[3][0] += x3 * wv.x; acc[3][1] += x3 * wv.y; acc[3][2] += x3 * wv.z; acc[3][3] += x3 * wv.w;
  }
#pragma unroll
  for (int i = 0; i < 4; ++i) {
    us[(r0 + i) * 33 + c0 + 0] = fmaxf(acc[i][0], 0.f);
    us[(r0 + i) * 33 + c0 + 1] = fmaxf(acc[i][1], 0.f);
    us[(r0 + i) * 33 + c0 + 2] = fmaxf(acc[i][2], 0.f);
    us[(r0 + i) * 33 + c0 + 3] = fmaxf(acc[i][3], 0.f);
  }
  __syncthreads();
#pragma unroll
  for (int i = 0; i < 4; ++i)
#pragma unroll
    for (int j = 0; j < 4; ++j) acc[i][j] = 0.f;
#pragma unroll
  for (int k = 0; k < H; ++k) {
    float4 wv = *(const float4*)&ws3[k * H + c0];
    float x0 = us[(r0 + 0) * 33 + k];
    float x1 = us[(r0 + 1) * 33 + k];
    float x2 = us[(r0 + 2) * 33 + k];
    float x3 = us[(r0 + 3) * 33 + k];
    acc[0][0] += x0 * wv.x; acc[0][1] += x0 * wv.y; acc[0][2] += x0 * wv.z; acc[0][3] += x0 * wv.w;
    acc[1][0] += x1 * wv.x; acc[1][1] += x1 * wv.y; acc[1][2] += x1 * wv.z; acc[1][3] += x1 * wv.w;
    acc[2][0] += x2 * wv.x; acc[2][1] += x2 * wv.y; acc[2][2] += x2 * wv.z; acc[2][3] += x2 * wv.w;
    acc[3][0] += x3 * wv.x; acc[3][1] += x3 * wv.y; acc[3][2] += x3 * wv.z; acc[3][3] += x3 * wv.w;
  }
#pragma unroll
  for (int i = 0; i < 4; ++i) {
    int gn = nb + r0 + i;
    if (gn < N)
      *(float4*)&y2[(size_t)gn * H + c0] = make_float4(acc[i][0], acc[i][1], acc[i][2], acc[i][3]);
  }
  // b3 is added during aggregation (linearity)
}

// h2 = relu(BN2(h2pre)) @ W4 + b4 (no trailing relu). Same tiling, one matmul.
__global__ __launch_bounds__(256) void k_mlp2(const float* __restrict__ hpre, const float* __restrict__ sc,
                                              const float* __restrict__ W4, const float* __restrict__ b4,
                                              float* __restrict__ h2, int N) {
  __shared__ __align__(16) float ws4[H * H];
  __shared__ __align__(16) float as[128 * 33];
  __shared__ float scs[2 * H], b4s[H];
  int t = threadIdx.x;
  for (int i = t; i < H * H; i += 256) ws4[i] = W4[i];
  if (t < 2 * H) scs[t] = sc[t];
  if (t < H) b4s[t] = b4[t];
  __syncthreads();
  int nb = blockIdx.x * 128;
  for (int i = t; i < 1024; i += 256) {
    int n = i >> 3, c4 = (i & 7) * 4;
    int gn = nb + n;
    float4 v = make_float4(0.f, 0.f, 0.f, 0.f);
    if (gn < N) v = *(const float4*)&hpre[(size_t)gn * H + c4];
    as[n * 33 + c4 + 0] = fmaxf(v.x * scs[c4 + 0] + scs[H + c4 + 0], 0.f);
    as[n * 33 + c4 + 1] = fmaxf(v.y * scs[c4 + 1] + scs[H + c4 + 1], 0.f);
    as[n * 33 + c4 + 2] = fmaxf(v.z * scs[c4 + 2] + scs[H + c4 + 2], 0.f);
    as[n * 33 + c4 + 3] = fmaxf(v.w * scs[c4 + 3] + scs[H + c4 + 3], 0.f);
  }
  __syncthreads();
  int r0 = (t >> 3) * 4, c0 = (t & 7) * 4;
  float acc[4][4];
#pragma unroll
  for (int i = 0; i < 4; ++i)
#pragma unroll
    for (int j = 0; j < 4; ++j) acc[i][j] = b4s[c0 + j];
#pragma unroll
  for (int k = 0; k < H; ++k) {
    float4 wv = *(const float4*)&ws4[k * H + c0];
    float x0 = as[(r0 + 0) * 33 + k];
    float x1 = as[(r0 + 1) * 33 + k];
    float x2 = as[(r0 + 2) * 33 + k];
    float x3 = as[(r0 + 3) * 33 + k];
    acc[0][0] += x0 * wv.x; acc[0][1] += x0 * wv.y; acc[0][2] += x0 * wv.z; acc[0][3] += x0 * wv.w;
    acc[1][0] += x1 * wv.x; acc[1][1] += x1 * wv.y; acc[1][2] += x1 * wv.z; acc[1][3] += x1 * wv.w;
    acc[2][0] += x2 * wv.x; acc[2][1] += x2 * wv.y; acc[2][2] += x2 * wv.z; acc[2][3] += x2 * wv.w;
    acc[3][0] += x3 * wv.x; acc[3][1] += x3 * wv.y; acc[3][2] += x3 * wv.z; acc[3][3] += x3 * wv.w;
  }
#pragma unroll
  for (int i = 0; i < 4; ++i) {
    int gn = nb + r0 + i;
    if (gn < N)
      *(float4*)&h2[(size_t)gn * H + c0] = make_float4(acc[i][0], acc[i][1], acc[i][2], acc[i][3]);
  }
}

// batch is sorted: graph g owns node range [lb(g), lb(g+1)). Wave per graph, mean||max -> z[G,64].
__global__ __launch_bounds__(256) void k_pool(const float* __restrict__ h2, const int* __restrict__ batch,
                                              int N, int G, float* __restrict__ z) {
  int wid = threadIdx.x >> 6, lane = threadIdx.x & 63;
  int g = blockIdx.x * 4 + wid;
  if (g >= G) return;
  int beg = lower_bound_i(batch, N, g);
  int end = lower_bound_i(batch, N, g + 1);
  int c = lane & 31, ep = lane >> 5;
  float s = 0.f, m = -3.402823466e38f;
  for (int i = beg + ep; i < end; i += 2) {
    float v = h2[(size_t)i * H + c];
    s += v; m = fmaxf(m, v);
  }
  s += __shfl_xor(s, 32, 64);
  m = fmaxf(m, __shfl_xor(m, 32, 64));
  if (ep == 0) {
    int cnt = end - beg;
    z[(size_t)g * 64 + c]     = (cnt > 0) ? s / (float)cnt : 0.f;
    z[(size_t)g * 64 + H + c] = (cnt > 0) ? m : 0.f;
  }
}

// out = relu(z @ Wc1 + bc1) @ Wc2 + bc2 ; thread per graph.
__global__ __launch_bounds__(256) void k_cls(const float* __restrict__ z, const float* __restrict__ Wc1,
                                             const float* __restrict__ bc1, const float* __restrict__ Wc2,
                                             const float* __restrict__ bc2, float* __restrict__ out, int G) {
  __shared__ __align__(16) float w1s[64 * H];
  __shared__ float w2s[H * 2], b1s[H], b2s[2];
  int t = threadIdx.x;
  for (int i = t; i < 64 * H; i += 256) w1s[i] = Wc1[i];
  if (t < H * 2) w2s[t] = Wc2[t];
  if (t < H) b1s[t] = bc1[t];
  if (t < 2) b2s[t] = bc2[t];
  __syncthreads();
  int g = blockIdx.x * 256 + t;
  if (g >= G) return;
  float zr[64], u[H];
  const float4* zp = (const float4*)&z[(size_t)g * 64];
#pragma unroll
  for (int q = 0; q < 16; ++q) {
    float4 v = zp[q];
    zr[q * 4 + 0] = v.x; zr[q * 4 + 1] = v.y; zr[q * 4 + 2] = v.z; zr[q * 4 + 3] = v.w;
  }
#pragma unroll
  for (int c = 0; c < H; ++c) u[c] = b1s[c];
#pragma unroll
  for (int k = 0; k < 64; ++k) {
    float av = zr[k];
    const float4* wr = (const float4*)&w1s[k * H];
#pragma unroll
    for (int q = 0; q < H / 4; ++q) {
      float4 wv = wr[q];
      u[q * 4 + 0] += av * wv.x; u[q * 4 + 1] += av * wv.y;
      u[q * 4 + 2] += av * wv.z; u[q * 4 + 3] += av * wv.w;
    }
  }
  float o0 = b2s[0], o1 = b2s[1];
#pragma unroll
  for (int k = 0; k < H; ++k) {
    float uv = fmaxf(u[k], 0.f);
    o0 += uv * w2s[k * 2 + 0];
    o1 += uv * w2s[k * 2 + 1];
  }
  out[(size_t)g * 2 + 0] = o0;
  out[(size_t)g * 2 + 1] = o1;
}

extern "C" void kernel_launch(void* const* d_in, const int* in_sizes, int n_in,
                              void* d_out, int out_size, void* d_ws, size_t ws_size,
                              hipStream_t stream) {
  const float* x    = (const float*)d_in[0];
  const int*   eidx = (const int*)d_in[1];
  const int*   batch= (const int*)d_in[2];
  const float* W1 = (const float*)d_in[3];
  const float* b1 = (const float*)d_in[4];
  const float* g1 = (const float*)d_in[5];
  const float* be1= (const float*)d_in[6];
  const float* W2 = (const float*)d_in[7];
  const float* b2 = (const float*)d_in[8];
  const float* W3 = (const float*)d_in[9];
  const float* b3 = (const float*)d_in[10];
  const float* g2 = (const float*)d_in[11];
  const float* be2= (const float*)d_in[12];
  const float* W4 = (const float*)d_in[13];
  const float* b4 = (const float*)d_in[14];
  const float* Wc1= (const float*)d_in[15];
  const float* bc1= (const float*)d_in[16];
  const float* Wc2= (const float*)d_in[17];
  const float* bc2= (const float*)d_in[18];
  (void)n_in; (void)ws_size;

  int N = in_sizes[2];       // 100000
  int E = in_sizes[1] / 2;   // 1600000
  int G = out_size / 2;      // 1000
  int nbuck = (N + BKT_SZ - 1) >> BKT_SHIFT;   // 196
  const int* srcv = eidx;
  const int* dstv = eidx + E;

  char* w = (char*)d_ws;
  auto carve = [&](size_t bytes) { void* p = (void*)w; w += (bytes + 255) & ~(size_t)255; return p; };
  float*    bufA    = (float*)carve((size_t)N * H * 4);      // y1 -> y2 -> h2
  float*    bufB    = (float*)carve((size_t)N * H * 4);      // h1 -> h2pre
  int*      row_ptr = (int*)carve((size_t)(N + 1) * 4);
  int*      csr     = (int*)carve((size_t)E * 4);
  unsigned* staging = (unsigned*)carve((size_t)E * 4);
  int*      gbcnt   = (int*)carve(256 * 4);
  int*      bbase   = (int*)carve(257 * 4);
  int*      bcur    = (int*)carve(256 * 4);
  float*    bnp     = (float*)carve((size_t)AGG_BLOCKS * 64 * 4);
  float*    bnp2    = (float*)carve((size_t)BNRED_NB * 64 * 4);
  float*    sc1     = (float*)carve(64 * 4);
  float*    sc2     = (float*)carve(64 * 4);
  float*    z       = (float*)carve((size_t)G * 64 * 4);

  int abk = (E + ACHUNK - 1) / ACHUNK;   // 391
  int tblk = (N + 127) / 128;            // 782

  hipMemsetAsync(gbcnt, 0, 256 * 4, stream);
  k_bhist<<<abk, 256, 0, stream>>>(dstv, E, gbcnt);
  k_bscan<<<1, 256, 0, stream>>>(gbcnt, nbuck, bbase, bcur);
  k_bucketA<<<abk, 256, 0, stream>>>(srcv, dstv, E, bcur, staging);
  k_bucketB<<<nbuck, 256, 0, stream>>>(staging, bbase, N, row_ptr, csr);
  k_gemm1<<<tblk, 256, 0, stream>>>(x, W1, bufA, N);
  k_agg<<<AGG_BLOCKS, 256, 0, stream>>>(bufA, b1, row_ptr, csr, bufB, bnp, N);
  k_bnred<<<BNRED_NB, 256, 0, stream>>>(bnp, bnp2);
  k_bnfin<<<1, 256, 0, stream>>>(bnp2, BNRED_NB, g1, be1, sc1, 1.0f / (float)N);
  k_mlp1<<<tblk, 256, 0, stream>>>(bufB, sc1, W2, b2, W3, bufA, N);
  k_agg<<<AGG_BLOCKS, 256, 0, stream>>>(bufA, b3, row_ptr, csr, bufB, bnp, N);
  k_bnred<<<BNRED_NB, 256, 0, stream>>>(bnp, bnp2);
  k_bnfin<<<1, 256, 0, stream>>>(bnp2, BNRED_NB, g2, be2, sc2, 1.0f / (float)N);
  k_mlp2<<<tblk, 256, 0, stream>>>(bufB, sc2, W4, b4, bufA, N);
  k_pool<<<(G + 3) / 4, 256, 0, stream>>>(bufA, batch, N, G, z);
  k_cls<<<(G + 255) / 256, 256, 0, stream>>>(z, Wc1, bc1, Wc2, bc2, (float*)d_out, G);
}